// Round 3
// baseline (1687.019 us; speedup 1.0000x reference)
//
#include <hip/hip_runtime.h>
#include <math.h>

// Problem constants
#define S_LEN 2048
#define HDIM  2048
#define NHEADS 16
#define NKVH   8
#define HD     128
#define FFDIM  6144
#define EPSV   1e-6f

// ---------------------------------------------------------------------------
// bf16 split helpers
// ---------------------------------------------------------------------------
__device__ __forceinline__ ushort f2bf(float f) {   // RNE
    unsigned u = __float_as_uint(f);
    u += 0x7FFF + ((u >> 16) & 1);
    return (ushort)(u >> 16);
}
__device__ __forceinline__ float bf2f(ushort h) {
    return __uint_as_float(((unsigned)h) << 16);
}

typedef __attribute__((ext_vector_type(8))) short bf16x8;
typedef __attribute__((ext_vector_type(4))) float f32x4;

__device__ __forceinline__ void glds16(const void* g, void* l) {
    __builtin_amdgcn_global_load_lds(
        (const __attribute__((address_space(1))) void*)g,
        (__attribute__((address_space(3))) void*)l, 16, 0, 0);
}

// ---------------------------------------------------------------------------
// RMSNorm over rows of 2048 -> bf16 hi/lo split output
// ---------------------------------------------------------------------------
__global__ __launch_bounds__(256) void rmsnorm_split_k(const float* __restrict__ in,
                                                       const float* __restrict__ w,
                                                       ushort* __restrict__ oh,
                                                       ushort* __restrict__ ol) {
    int s = blockIdx.x;
    int tid = threadIdx.x;
    const float* row = in + (size_t)s * HDIM;
    float ss = 0.0f;
    for (int i = tid; i < HDIM; i += 256) {
        float v = row[i];
        ss += v * v;
    }
    __shared__ float red[256];
    red[tid] = ss;
    __syncthreads();
    for (int off = 128; off > 0; off >>= 1) {
        if (tid < off) red[tid] += red[tid + off];
        __syncthreads();
    }
    float r = rsqrtf(red[0] / (float)HDIM + EPSV);
    for (int i = tid; i < HDIM; i += 256) {
        float v = row[i] * r * w[i];
        ushort h = f2bf(v);
        oh[(size_t)s * HDIM + i] = h;
        ol[(size_t)s * HDIM + i] = f2bf(v - bf2f(h));
    }
}

// ---------------------------------------------------------------------------
// Elementwise fp32 -> bf16 hi/lo split
// ---------------------------------------------------------------------------
__global__ __launch_bounds__(256) void split_k(const float* __restrict__ in,
                                               ushort* __restrict__ oh,
                                               ushort* __restrict__ ol, int n) {
    int i = blockIdx.x * 256 + threadIdx.x;
    if (i < n) {
        float v = in[i];
        ushort h = f2bf(v);
        oh[i] = h;
        ol[i] = f2bf(v - bf2f(h));
    }
}

// ---------------------------------------------------------------------------
// K conversion: fp32 [S][NKVH][HD] -> bf16 hi/lo, d-index XOR-swizzled per row
// (d ^= (s&7)<<3) so linear glds16 staging yields a conflict-free LDS tile.
// ---------------------------------------------------------------------------
__global__ __launch_bounds__(256) void conv_k_swz_k(const float* __restrict__ in,
                                                    ushort* __restrict__ oh,
                                                    ushort* __restrict__ ol) {
    int i = blockIdx.x * 256 + threadIdx.x;      // over S*NKVH*HD = 2M
    int s = i >> 10;                              // NKVH*HD = 1024
    int d = i & 127;
    int base = i & ~127;
    float v = in[i];
    unsigned u = __float_as_uint(v);
    float hi = __uint_as_float(u & 0xFFFF0000u);
    int o = base + (d ^ ((s & 7) << 3));
    oh[o] = (ushort)(u >> 16);
    ol[o] = (ushort)(__float_as_uint(v - hi) >> 16);
}

// ---------------------------------------------------------------------------
// V conversion + transpose: fp32 [S][NKVH][HD] -> bf16 hi/lo [NKVH][HD][S],
// s-index XOR-swizzled within each 64-block (s ^= (d&7)<<3).
// ---------------------------------------------------------------------------
__global__ __launch_bounds__(256) void conv_vt_k(const float* __restrict__ v,
                                                 ushort* __restrict__ oh,
                                                 ushort* __restrict__ ol) {
    __shared__ float t[64][65];
    int s0 = blockIdx.x * 64, d0 = blockIdx.y * 64, kvh = blockIdx.z;
    int tid = threadIdx.x;
#pragma unroll
    for (int p = 0; p < 4; ++p) {
        int c = tid + p * 256;
        int ss = c >> 4, d4 = (c & 15) * 4;
        float4 x = *(const float4*)&v[((size_t)(s0 + ss) * NKVH + kvh) * HD + d0 + d4];
        t[d4 + 0][ss] = x.x;
        t[d4 + 1][ss] = x.y;
        t[d4 + 2][ss] = x.z;
        t[d4 + 3][ss] = x.w;
    }
    __syncthreads();
#pragma unroll
    for (int p = 0; p < 4; ++p) {
        int c = tid + p * 256;
        int dd = c >> 4, s4 = (c & 15) * 4;
        int d = d0 + dd;
        int sx = s4 ^ ((d & 7) << 3);
        size_t obase = ((size_t)kvh * HD + d) * S_LEN + s0 + sx;
        ushort4 hv, lv;
        float a0 = t[dd][s4 + 0], a1 = t[dd][s4 + 1], a2 = t[dd][s4 + 2], a3 = t[dd][s4 + 3];
        unsigned u0 = __float_as_uint(a0), u1 = __float_as_uint(a1);
        unsigned u2 = __float_as_uint(a2), u3 = __float_as_uint(a3);
        hv.x = (ushort)(u0 >> 16); lv.x = (ushort)(__float_as_uint(a0 - __uint_as_float(u0 & 0xFFFF0000u)) >> 16);
        hv.y = (ushort)(u1 >> 16); lv.y = (ushort)(__float_as_uint(a1 - __uint_as_float(u1 & 0xFFFF0000u)) >> 16);
        hv.z = (ushort)(u2 >> 16); lv.z = (ushort)(__float_as_uint(a2 - __uint_as_float(u2 & 0xFFFF0000u)) >> 16);
        hv.w = (ushort)(u3 >> 16); lv.w = (ushort)(__float_as_uint(a3 - __uint_as_float(u3 & 0xFFFF0000u)) >> 16);
        *(ushort4*)&oh[obase] = hv;
        *(ushort4*)&ol[obase] = lv;
    }
}

// ---------------------------------------------------------------------------
// Transpose + split: W[K][Ntot] (cols n0..n0+Nc) -> Th/Tl [Nc][K] bf16
// ---------------------------------------------------------------------------
__global__ __launch_bounds__(256) void transpose_split_k(const float* __restrict__ W,
                                                         ushort* __restrict__ Th,
                                                         ushort* __restrict__ Tl,
                                                         int K, int Ntot, int n0) {
    __shared__ float t[64][65];
    int tid = threadIdx.x;
    int nt = blockIdx.x * 64;
    int kt = blockIdx.y * 64;
#pragma unroll
    for (int p = 0; p < 4; ++p) {
        int idx = tid + p * 256;
        int kk = idx >> 4;
        int nn = (idx & 15) * 4;
        float4 v = *(const float4*)&W[(size_t)(kt + kk) * Ntot + n0 + nt + nn];
        t[nn + 0][kk] = v.x;
        t[nn + 1][kk] = v.y;
        t[nn + 2][kk] = v.z;
        t[nn + 3][kk] = v.w;
    }
    __syncthreads();
#pragma unroll
    for (int p = 0; p < 4; ++p) {
        int idx = tid + p * 256;
        int nn = idx >> 4;
        int kk = (idx & 15) * 4;
        ushort4 hv, lv;
        float a0 = t[nn][kk + 0], a1 = t[nn][kk + 1], a2 = t[nn][kk + 2], a3 = t[nn][kk + 3];
        hv.x = f2bf(a0); lv.x = f2bf(a0 - bf2f(hv.x));
        hv.y = f2bf(a1); lv.y = f2bf(a1 - bf2f(hv.y));
        hv.z = f2bf(a2); lv.z = f2bf(a2 - bf2f(hv.z));
        hv.w = f2bf(a3); lv.w = f2bf(a3 - bf2f(hv.w));
        size_t o = (size_t)(nt + nn) * K + kt + kk;
        *(ushort4*)&Th[o] = hv;
        *(ushort4*)&Tl[o] = lv;
    }
}

// ---------------------------------------------------------------------------
// bf16x3 compensated MFMA GEMM, BM=BN=128, BK=32, 4 waves (each 64x64).
//   Per wave per K-step: 48 MFMA (240cy) vs 16 ds_read_b128 (192cy) -> MFMA-
//   bound. LDS 32 KB. glds16 width-16 staging, linear layout (m97 pattern).
//   MODE 0: C = acc (+ res)    MODE 1: d = silu(gbuf)*acc -> Dh/Dl bf16 split
// ---------------------------------------------------------------------------
template <int MODE>
__global__ __launch_bounds__(256, 3) void gemm_bf16x3(
    const ushort* __restrict__ Ah, const ushort* __restrict__ Al,
    const ushort* __restrict__ Bh, const ushort* __restrict__ Bl,
    const float* res, const float* __restrict__ gbuf,
    float* C, ushort* __restrict__ Dh, ushort* __restrict__ Dl,
    int M, int N, int K) {
    __shared__ __align__(16) ushort sAh[128 * 32];
    __shared__ __align__(16) ushort sAl[128 * 32];
    __shared__ __align__(16) ushort sBh[128 * 32];
    __shared__ __align__(16) ushort sBl[128 * 32];

    // bijective XCD swizzle (grid size is a multiple of 8)
    unsigned nbx = gridDim.x;
    unsigned flat = blockIdx.y * nbx + blockIdx.x;
    unsigned cpx = (nbx * gridDim.y) >> 3;
    unsigned sflat = (flat & 7u) * cpx + (flat >> 3);
    int bx = (int)(sflat % nbx);
    int by = (int)(sflat / nbx);
    int bm = by * 128, bn = bx * 128;

    int tid = threadIdx.x;
    int lane = tid & 63, wave = tid >> 6;
    int wr = wave >> 1, wc = wave & 1;
    int r = lane & 15, kq = lane >> 4;

    // staging: each tile (128x32 bf16 = 8KB) = 512 16B-chunks = 2/thread
    int srow = tid >> 2;
    int sk = (tid & 3) * 8;
    const ushort* gA0h = Ah + (size_t)(bm + srow) * K + sk;
    const ushort* gA0l = Al + (size_t)(bm + srow) * K + sk;
    const ushort* gB0h = Bh + (size_t)(bn + srow) * K + sk;
    const ushort* gB0l = Bl + (size_t)(bn + srow) * K + sk;
    const size_t rstep = (size_t)64 * K;   // +64 rows for second chunk

    const ushort* pAh = sAh + (wr * 64 + r) * 32 + kq * 8;
    const ushort* pAl = sAl + (wr * 64 + r) * 32 + kq * 8;
    const ushort* pBh = sBh + (wc * 64 + r) * 32 + kq * 8;
    const ushort* pBl = sBl + (wc * 64 + r) * 32 + kq * 8;

    f32x4 acc[4][4] = {};

    for (int k0 = 0; k0 < K; k0 += 32) {
        glds16(gA0h, sAh + tid * 8);
        glds16(gA0h + rstep, sAh + 2048 + tid * 8);
        glds16(gA0l, sAl + tid * 8);
        glds16(gA0l + rstep, sAl + 2048 + tid * 8);
        glds16(gB0h, sBh + tid * 8);
        glds16(gB0h + rstep, sBh + 2048 + tid * 8);
        glds16(gB0l, sBl + tid * 8);
        glds16(gB0l + rstep, sBl + 2048 + tid * 8);
        gA0h += 32; gA0l += 32; gB0h += 32; gB0l += 32;
        __syncthreads();   // barrier drains vmcnt -> tiles resident

        bf16x8 ah[4], al[4];
#pragma unroll
        for (int mi = 0; mi < 4; ++mi) {
            ah[mi] = *(const bf16x8*)(pAh + mi * 512);
            al[mi] = *(const bf16x8*)(pAl + mi * 512);
        }
#pragma unroll
        for (int ni = 0; ni < 4; ++ni) {
            bf16x8 bh = *(const bf16x8*)(pBh + ni * 512);
            bf16x8 bl = *(const bf16x8*)(pBl + ni * 512);
#pragma unroll
            for (int mi = 0; mi < 4; ++mi) {
                acc[mi][ni] = __builtin_amdgcn_mfma_f32_16x16x32_bf16(ah[mi], bh, acc[mi][ni], 0, 0, 0);
                acc[mi][ni] = __builtin_amdgcn_mfma_f32_16x16x32_bf16(al[mi], bh, acc[mi][ni], 0, 0, 0);
                acc[mi][ni] = __builtin_amdgcn_mfma_f32_16x16x32_bf16(ah[mi], bl, acc[mi][ni], 0, 0, 0);
            }
        }
        __syncthreads();   // all reads done before next stage overwrites
    }

    // epilogue; C/D layout: col = lane&15, row = (lane>>4)*4 + j
    int c0 = bn + wc * 64 + r;
    int r0 = bm + wr * 64 + kq * 4;
#pragma unroll
    for (int mi = 0; mi < 4; ++mi)
#pragma unroll
        for (int ni = 0; ni < 4; ++ni)
#pragma unroll
            for (int j = 0; j < 4; ++j) {
                int row = r0 + mi * 16 + j;
                int col = c0 + ni * 16;
                size_t idx = (size_t)row * N + col;
                float val = acc[mi][ni][j];
                if (MODE == 0) {
                    if (res) val += res[idx];
                    C[idx] = val;
                } else {
                    float gv = gbuf[idx];
                    float dv = gv / (1.0f + expf(-gv)) * val;
                    ushort hh = f2bf(dv);
                    Dh[idx] = hh;
                    Dl[idx] = f2bf(dv - bf2f(hh));
                }
            }
}

// ---------------------------------------------------------------------------
// Per-head RMSNorm (over HD=128) + RoPE, in place.
// ---------------------------------------------------------------------------
__global__ __launch_bounds__(128) void qk_norm_rope_k(float* __restrict__ qk,
                                                      const float* __restrict__ nw,
                                                      const int* __restrict__ positions,
                                                      int nheads) {
    int s = blockIdx.x;
    int h = blockIdx.y;
    int d = threadIdx.x;
    float* row = qk + ((size_t)s * nheads + h) * HD;
    __shared__ float buf[HD];
    __shared__ float red[HD];
    float v = row[d];
    red[d] = v * v;
    __syncthreads();
    for (int off = 64; off > 0; off >>= 1) {
        if (d < off) red[d] += red[d + off];
        __syncthreads();
    }
    float r = rsqrtf(red[0] / (float)HD + EPSV);
    float nv = v * r * nw[d];
    buf[d] = nv;
    __syncthreads();
    float pos = (float)positions[s];
    int d2 = d & 63;
    float inv_freq = expf(-((float)(2 * d2) / 128.0f) * 13.815510557964274f);
    float freq = pos * inv_freq;
    float c, sn;
    sincosf(freq, &sn, &c);
    float rot = (d < 64) ? -buf[d + 64] : buf[d - 64];
    row[d] = nv * c + rot * sn;
}

// ---------------------------------------------------------------------------
// MFMA flash attention, bf16x3 compensated (verified round 1).
// Epilogue now writes ctx as bf16 hi/lo split directly (feeds o-proj GEMM).
// ---------------------------------------------------------------------------
#define ATQ 64
#define ATK 64

__global__ __launch_bounds__(256, 2) void attn_mfma_k(
    const ushort* __restrict__ Qhg, const ushort* __restrict__ Qlg,
    const ushort* __restrict__ Khg, const ushort* __restrict__ Klg,
    const ushort* __restrict__ Vhg, const ushort* __restrict__ Vlg,
    const int* __restrict__ keys_idxs, const int* __restrict__ hs_idxs,
    ushort* __restrict__ Chg, ushort* __restrict__ Clg) {
    __shared__ __align__(16) ushort sKh[64 * 128];   // also P overlay (4 x 2048)
    __shared__ __align__(16) ushort sKl[64 * 128];
    __shared__ __align__(16) ushort sVh[128 * 64];
    __shared__ __align__(16) ushort sVl[128 * 64];
    __shared__ int kidx[ATK];
    __shared__ int qpos[ATQ];

    int bx = blockIdx.x;
    int qt = (bx & 1) ? (31 - (bx >> 1)) : (bx >> 1);
    int h = blockIdx.y;
    int kvh = h >> 1;
    int tid = threadIdx.x;
    int lane = tid & 63, wv = tid >> 6;
    int q0 = qt * ATQ;
    int r = lane & 15, kq = lane >> 4;
    int xorv = (lane & 7) << 3;
    const float scale = 0.088388347648318447f;

    bf16x8 qh[4], ql[4];
    {
        const ushort* qb = Qhg + ((size_t)(q0 + wv * 16 + r) * NHEADS + h) * HD + kq * 8;
        const ushort* qb2 = Qlg + ((size_t)(q0 + wv * 16 + r) * NHEADS + h) * HD + kq * 8;
#pragma unroll
        for (int ks = 0; ks < 4; ++ks) {
            qh[ks] = *(const bf16x8*)(qb + ks * 32);
            ql[ks] = *(const bf16x8*)(qb2 + ks * 32);
        }
    }
    if (tid < ATQ) qpos[tid] = hs_idxs[q0 + tid];

    const size_t kvstride = (size_t)NKVH * HD;   // 1024
    const ushort* gKh = Khg + ((size_t)(tid >> 4) * NKVH + kvh) * HD + (tid & 15) * 8;
    const ushort* gKl = Klg + ((size_t)(tid >> 4) * NKVH + kvh) * HD + (tid & 15) * 8;
    const ushort* gVh = Vhg + ((size_t)kvh * HD + (tid >> 3)) * S_LEN + (tid & 7) * 8;
    const ushort* gVl = Vlg + ((size_t)kvh * HD + (tid >> 3)) * S_LEN + (tid & 7) * 8;

    f32x4 o[8] = {};
    float m_run[4] = {-3.0e38f, -3.0e38f, -3.0e38f, -3.0e38f};
    float l_run[4] = {0.0f, 0.0f, 0.0f, 0.0f};

    __syncthreads();
    int hs_max = qpos[ATQ - 1];
    int qp[4];
#pragma unroll
    for (int j = 0; j < 4; ++j) qp[j] = qpos[wv * 16 + kq * 4 + j];

    for (int kt = 0; kt < S_LEN / ATK; ++kt) {
        int k0 = kt * ATK;
        if (keys_idxs[k0] > hs_max) break;
        __syncthreads();
        const size_t koff = (size_t)k0 * kvstride;
#pragma unroll
        for (int p = 0; p < 4; ++p) {
            glds16(gKh + koff + (size_t)p * 16 * kvstride, sKh + (tid + p * 256) * 8);
            glds16(gKl + koff + (size_t)p * 16 * kvstride, sKl + (tid + p * 256) * 8);
            glds16(gVh + k0 + (size_t)p * 32 * S_LEN, sVh + (tid + p * 256) * 8);
            glds16(gVl + k0 + (size_t)p * 32 * S_LEN, sVl + (tid + p * 256) * 8);
        }
        if (tid < ATK) kidx[tid] = keys_idxs[k0 + tid];
        __syncthreads();

        f32x4 sf[4] = {};
#pragma unroll
        for (int ks = 0; ks < 4; ++ks) {
            int kb = (ks * 32 + kq * 8) ^ xorv;
#pragma unroll
            for (int f = 0; f < 4; ++f) {
                bf16x8 kh = *(const bf16x8*)(sKh + (f * 16 + r) * 128 + kb);
                bf16x8 kl = *(const bf16x8*)(sKl + (f * 16 + r) * 128 + kb);
                sf[f] = __builtin_amdgcn_mfma_f32_16x16x32_bf16(qh[ks], kh, sf[f], 0, 0, 0);
                sf[f] = __builtin_amdgcn_mfma_f32_16x16x32_bf16(ql[ks], kh, sf[f], 0, 0, 0);
                sf[f] = __builtin_amdgcn_mfma_f32_16x16x32_bf16(qh[ks], kl, sf[f], 0, 0, 0);
            }
        }

        int kj[4];
#pragma unroll
        for (int f = 0; f < 4; ++f) kj[f] = kidx[f * 16 + r];
        float alj[4];
#pragma unroll
        for (int j = 0; j < 4; ++j) {
#pragma unroll
            for (int f = 0; f < 4; ++f)
                sf[f][j] = sf[f][j] * scale + ((kj[f] <= qp[j]) ? 0.0f : -1.0e9f);
            float m0 = fmaxf(fmaxf(sf[0][j], sf[1][j]), fmaxf(sf[2][j], sf[3][j]));
#pragma unroll
            for (int off = 1; off < 16; off <<= 1) m0 = fmaxf(m0, __shfl_xor(m0, off));
            float mn = fmaxf(m_run[j], m0);
            alj[j] = __expf(m_run[j] - mn);
            m_run[j] = mn;
            float rsum = 0.0f;
#pragma unroll
            for (int f = 0; f < 4; ++f) {
                sf[f][j] = __expf(sf[f][j] - mn);
                rsum += sf[f][j];
            }
#pragma unroll
            for (int off = 1; off < 16; off <<= 1) rsum += __shfl_xor(rsum, off);
            l_run[j] = l_run[j] * alj[j] + rsum;
        }
#pragma unroll
        for (int df = 0; df < 8; ++df)
#pragma unroll
            for (int j = 0; j < 4; ++j) o[df][j] *= alj[j];

        __syncthreads();

        ushort* sPh = sKh + wv * 2048;
        ushort* sPl = sPh + 1024;
#pragma unroll
        for (int j = 0; j < 4; ++j) {
            int qloc = kq * 4 + j;
            int swz = (qloc & 7) << 3;
            int rowb = qloc * 64;
#pragma unroll
            for (int f = 0; f < 4; ++f) {
                float pv = sf[f][j];
                unsigned u = __float_as_uint(pv);
                float hi = __uint_as_float(u & 0xFFFF0000u);
                int a = rowb + ((f * 16 + r) ^ swz);
                sPh[a] = (ushort)(u >> 16);
                sPl[a] = (ushort)(__float_as_uint(pv - hi) >> 16);
            }
        }

#pragma unroll
        for (int kv0 = 0; kv0 < 2; ++kv0) {
            int kb = (kv0 * 32 + kq * 8) ^ xorv;
            bf16x8 pah = *(const bf16x8*)(sPh + r * 64 + kb);
            bf16x8 pal = *(const bf16x8*)(sPl + r * 64 + kb);
#pragma unroll
            for (int df = 0; df < 8; ++df) {
                bf16x8 vh = *(const bf16x8*)(sVh + (df * 16 + r) * 64 + kb);
                bf16x8 vl = *(const bf16x8*)(sVl + (df * 16 + r) * 64 + kb);
                o[df] = __builtin_amdgcn_mfma_f32_16x16x32_bf16(pah, vh, o[df], 0, 0, 0);
                o[df] = __builtin_amdgcn_mfma_f32_16x16x32_bf16(pal, vh, o[df], 0, 0, 0);
                o[df] = __builtin_amdgcn_mfma_f32_16x16x32_bf16(pah, vl, o[df], 0, 0, 0);
            }
        }
    }

    // epilogue: normalize + bf16 hi/lo split store (feeds o-proj A operand)
#pragma unroll
    for (int j = 0; j < 4; ++j) {
        float invl = 1.0f / l_run[j];
        int qg = q0 + wv * 16 + kq * 4 + j;
#pragma unroll
        for (int df = 0; df < 8; ++df) {
            int d = df * 16 + r;
            float val = o[df][j] * invl;
            size_t idx = ((size_t)qg * NHEADS + h) * HD + d;
            ushort hh = f2bf(val);
            Chg[idx] = hh;
            Clg[idx] = f2bf(val - bf2f(hh));
        }
    }
}

// ---------------------------------------------------------------------------
// Importance: softmax (no mask) of last q row vs all keys, per head. (fp32)
// ---------------------------------------------------------------------------
__global__ __launch_bounds__(256) void importance_scores_k(const float* __restrict__ q,
                                                           const float* __restrict__ k,
                                                           float* __restrict__ imp_ws) {
    int h = blockIdx.x;
    int kv = h >> 1;
    int tid = threadIdx.x;
    __shared__ float qrow[HD];
    __shared__ float sc[S_LEN];
    __shared__ float red[256];
    const float* qp = q + ((size_t)(S_LEN - 1) * NHEADS + h) * HD;
    if (tid < HD) qrow[tid] = qp[tid];
    __syncthreads();
    const float scale = 0.088388347648318447f;
    float lmax = -3.0e38f;
#pragma unroll
    for (int rep = 0; rep < 8; ++rep) {
        int j = tid + rep * 256;
        const float* kp = k + ((size_t)j * NKVH + kv) * HD;
        float dot = 0.0f;
        for (int d = 0; d < HD; ++d) dot += qrow[d] * kp[d];
        float sval = dot * scale;
        sc[j] = sval;
        lmax = fmaxf(lmax, sval);
    }
    red[tid] = lmax;
    __syncthreads();
    for (int off = 128; off > 0; off >>= 1) {
        if (tid < off) red[tid] = fmaxf(red[tid], red[tid + off]);
        __syncthreads();
    }
    float m = red[0];
    __syncthreads();
    float lsum = 0.0f;
    float evals[8];
#pragma unroll
    for (int rep = 0; rep < 8; ++rep) {
        int j = tid + rep * 256;
        float e = expf(sc[j] - m);
        evals[rep] = e;
        lsum += e;
    }
    red[tid] = lsum;
    __syncthreads();
    for (int off = 128; off > 0; off >>= 1) {
        if (tid < off) red[tid] += red[tid + off];
        __syncthreads();
    }
    float inv = 1.0f / red[0];
#pragma unroll
    for (int rep = 0; rep < 8; ++rep) {
        int j = tid + rep * 256;
        imp_ws[(size_t)h * S_LEN + j] = evals[rep] * inv;
    }
}

__global__ __launch_bounds__(256) void importance_combine_k(const float* __restrict__ imp_ws,
                                                            float* __restrict__ out) {
    int j = blockIdx.x * 256 + threadIdx.x;
    float sum = 0.0f;
    for (int h = 0; h < NHEADS; ++h) sum += imp_ws[(size_t)h * S_LEN + j];
    out[j] = (j == S_LEN - 1) ? 3.0e38f : sum * (1.0f / NHEADS);
}

// ---------------------------------------------------------------------------
extern "C" void kernel_launch(void* const* d_in, const int* in_sizes, int n_in,
                              void* d_out, int out_size, void* d_ws, size_t ws_size,
                              hipStream_t stream) {
    const float* hidden    = (const float*)d_in[0];
    const int*   keys_idxs = (const int*)d_in[2];
    const int*   hs_idxs   = (const int*)d_in[3];
    const int*   positions = (const int*)d_in[4];
    const float* ln_in_w   = (const float*)d_in[5];
    const float* q_w       = (const float*)d_in[6];
    const float* k_w       = (const float*)d_in[7];
    const float* v_w       = (const float*)d_in[8];
    const float* q_norm_w  = (const float*)d_in[9];
    const float* k_norm_w  = (const float*)d_in[10];
    const float* o_w       = (const float*)d_in[11];
    const float* ln_post_w = (const float*)d_in[12];
    const float* gate_w    = (const float*)d_in[13];
    const float* up_w      = (const float*)d_in[14];
    const float* down_w    = (const float*)d_in[15];

    float* out = (float*)d_out;
    float* ws = (float*)d_ws;
    const size_t MF = 1024ull * 1024;

    // Region plan (floats; peak 20 MF = 80 MB):
    //  [0,4M)    Xh/Xl bf16        -> Qbh/Qbl bf16 (X dead after v GEMM)
    //  [4M,8M)   Wh/Wl bf16        -> imp scratch -> Kbh/Kbl + Vth/Vtl -> Wh/Wl
    //  [8M,12M)  q fp32            -> Ch/Cl bf16 (attn out) -> g chunk fp32
    //  [12M,14M) k fp32            \_ h fp32 -> D chunk Dh/Dl
    //  [14M,16M) v fp32            /
    //  [16M,20M) ctx (unused now)  -> Yh/Yl bf16
    ushort* Xh = (ushort*)(ws);
    ushort* Xl = (ushort*)(ws + 2 * MF);
    ushort* Wh = (ushort*)(ws + 4 * MF);
    ushort* Wl = (ushort*)(ws + 6 * MF);
    float*  qb  = ws + 8 * MF;
    float*  kbf = ws + 12 * MF;
    float*  vbf = ws + 14 * MF;
    ushort* Qbh = (ushort*)(ws);
    ushort* Qbl = (ushort*)(ws + 2 * MF);
    float*  imp = ws + 4 * MF;
    ushort* Kbh = (ushort*)(ws + 4 * MF);
    ushort* Kbl = (ushort*)(ws + 5 * MF);
    ushort* Vth = (ushort*)(ws + 6 * MF);
    ushort* Vtl = (ushort*)(ws + 7 * MF);
    ushort* Ch = (ushort*)(ws + 8 * MF);
    ushort* Cl = (ushort*)(ws + 10 * MF);
    float*  hb = ws + 12 * MF;
    ushort* Yh = (ushort*)(ws + 16 * MF);
    ushort* Yl = (ushort*)(ws + 18 * MF);
    float*  gb = ws + 8 * MF;
    ushort* Dh = (ushort*)(ws + 12 * MF);
    ushort* Dl = (ushort*)(ws + 14 * MF);

    // 1. x = rms(hidden) -> bf16 split
    rmsnorm_split_k<<<S_LEN, 256, 0, stream>>>(hidden, ln_in_w, Xh, Xl);

    // 2. q/k/v projections (MFMA bf16x3, 128x128 tiles)
    transpose_split_k<<<dim3(32, 32), 256, 0, stream>>>(q_w, Wh, Wl, HDIM, HDIM, 0);
    gemm_bf16x3<0><<<dim3(HDIM / 128, S_LEN / 128), 256, 0, stream>>>(
        Xh, Xl, Wh, Wl, nullptr, nullptr, qb, nullptr, nullptr, S_LEN, HDIM, HDIM);

    transpose_split_k<<<dim3(16, 32), 256, 0, stream>>>(k_w, Wh, Wl, HDIM, 1024, 0);
    gemm_bf16x3<0><<<dim3(1024 / 128, S_LEN / 128), 256, 0, stream>>>(
        Xh, Xl, Wh, Wl, nullptr, nullptr, kbf, nullptr, nullptr, S_LEN, 1024, HDIM);

    transpose_split_k<<<dim3(16, 32), 256, 0, stream>>>(v_w, Wh, Wl, HDIM, 1024, 0);
    gemm_bf16x3<0><<<dim3(1024 / 128, S_LEN / 128), 256, 0, stream>>>(
        Xh, Xl, Wh, Wl, nullptr, nullptr, vbf, nullptr, nullptr, S_LEN, 1024, HDIM);

    // 3. per-head norm + rope (fp32, in place)
    qk_norm_rope_k<<<dim3(S_LEN, NHEADS), 128, 0, stream>>>(qb, q_norm_w, positions, NHEADS);
    qk_norm_rope_k<<<dim3(S_LEN, NKVH), 128, 0, stream>>>(kbf, k_norm_w, positions, NKVH);

    // 4. importance (fp32 q,k; before conversions overwrite scratch)
    importance_scores_k<<<NHEADS, 256, 0, stream>>>(qb, kbf, imp);
    importance_combine_k<<<S_LEN / 256, 256, 0, stream>>>(imp, out + (size_t)S_LEN * HDIM);

    // 5. convert q/k/v to bf16 hi/lo attention layouts
    split_k<<<(S_LEN * NHEADS * HD) / 256, 256, 0, stream>>>(qb, Qbh, Qbl, S_LEN * NHEADS * HD);
    conv_k_swz_k<<<(S_LEN * NKVH * HD) / 256, 256, 0, stream>>>(kbf, Kbh, Kbl);
    conv_vt_k<<<dim3(S_LEN / 64, HD / 64, NKVH), 256, 0, stream>>>(vbf, Vth, Vtl);

    // 6. MFMA flash attention -> Ch/Cl (bf16 split, q region now dead)
    attn_mfma_k<<<dim3(S_LEN / ATQ, NHEADS), 256, 0, stream>>>(
        Qbh, Qbl, Kbh, Kbl, Vth, Vtl, keys_idxs, hs_idxs, Ch, Cl);

    // 7. h = hidden + ctx @ o_w
    transpose_split_k<<<dim3(32, 32), 256, 0, stream>>>(o_w, Wh, Wl, HDIM, HDIM, 0);
    gemm_bf16x3<0><<<dim3(HDIM / 128, S_LEN / 128), 256, 0, stream>>>(
        Ch, Cl, Wh, Wl, hidden, nullptr, hb, nullptr, nullptr, S_LEN, HDIM, HDIM);

    // 8. out = h (residual base for chunked down-proj accumulation)
    hipMemcpyAsync(out, hb, (size_t)S_LEN * HDIM * sizeof(float),
                   hipMemcpyDeviceToDevice, stream);

    // 9. y = rms(h) -> bf16 split
    rmsnorm_split_k<<<S_LEN, 256, 0, stream>>>(hb, ln_post_w, Yh, Yl);

    // 10. MLP in three FF-chunks of 2048 (fused silu epilogue)
    for (int c = 0; c < 3; ++c) {
        transpose_split_k<<<dim3(32, 32), 256, 0, stream>>>(gate_w, Wh, Wl, HDIM, FFDIM, c * 2048);
        gemm_bf16x3<0><<<dim3(16, 16), 256, 0, stream>>>(
            Yh, Yl, Wh, Wl, nullptr, nullptr, gb, nullptr, nullptr, S_LEN, 2048, HDIM);
        transpose_split_k<<<dim3(32, 32), 256, 0, stream>>>(up_w, Wh, Wl, HDIM, FFDIM, c * 2048);
        gemm_bf16x3<1><<<dim3(16, 16), 256, 0, stream>>>(
            Yh, Yl, Wh, Wl, nullptr, gb, nullptr, Dh, Dl, S_LEN, 2048, HDIM);
        transpose_split_k<<<dim3(32, 32), 256, 0, stream>>>(
            down_w + (size_t)c * 2048 * HDIM, Wh, Wl, 2048, HDIM, 0);
        gemm_bf16x3<0><<<dim3(16, 16), 256, 0, stream>>>(
            Dh, Dl, Wh, Wl, out, nullptr, out, nullptr, nullptr, S_LEN, HDIM, 2048);
    }
}

// Round 4
// 1361.633 us; speedup vs baseline: 1.2390x; 1.2390x over previous
//
#include <hip/hip_runtime.h>
#include <math.h>

// Problem constants
#define S_LEN 2048
#define HDIM  2048
#define NHEADS 16
#define NKVH   8
#define HD     128
#define FFDIM  6144
#define EPSV   1e-6f

// ---------------------------------------------------------------------------
// bf16 split helpers
// ---------------------------------------------------------------------------
__device__ __forceinline__ ushort f2bf(float f) {   // RNE
    unsigned u = __float_as_uint(f);
    u += 0x7FFF + ((u >> 16) & 1);
    return (ushort)(u >> 16);
}
__device__ __forceinline__ float bf2f(ushort h) {
    return __uint_as_float(((unsigned)h) << 16);
}

typedef __attribute__((ext_vector_type(8))) short bf16x8;
typedef __attribute__((ext_vector_type(4))) float f32x4;

__device__ __forceinline__ void glds16(const void* g, void* l) {
    __builtin_amdgcn_global_load_lds(
        (const __attribute__((address_space(1))) void*)g,
        (__attribute__((address_space(3))) void*)l, 16, 0, 0);
}

// ---------------------------------------------------------------------------
// RMSNorm over rows of 2048 -> bf16 hi/lo split output
// ---------------------------------------------------------------------------
__global__ __launch_bounds__(256) void rmsnorm_split_k(const float* __restrict__ in,
                                                       const float* __restrict__ w,
                                                       ushort* __restrict__ oh,
                                                       ushort* __restrict__ ol) {
    int s = blockIdx.x;
    int tid = threadIdx.x;
    const float* row = in + (size_t)s * HDIM;
    float ss = 0.0f;
    for (int i = tid; i < HDIM; i += 256) {
        float v = row[i];
        ss += v * v;
    }
    __shared__ float red[256];
    red[tid] = ss;
    __syncthreads();
    for (int off = 128; off > 0; off >>= 1) {
        if (tid < off) red[tid] += red[tid + off];
        __syncthreads();
    }
    float r = rsqrtf(red[0] / (float)HDIM + EPSV);
    for (int i = tid; i < HDIM; i += 256) {
        float v = row[i] * r * w[i];
        ushort h = f2bf(v);
        oh[(size_t)s * HDIM + i] = h;
        ol[(size_t)s * HDIM + i] = f2bf(v - bf2f(h));
    }
}

// ---------------------------------------------------------------------------
// Q conversion: strided fp32 [S][4096] cols 0..2047 -> bf16 hi/lo [S][2048]
// ---------------------------------------------------------------------------
__global__ __launch_bounds__(256) void conv_q_k(const float* __restrict__ in,
                                                ushort* __restrict__ oh,
                                                ushort* __restrict__ ol) {
    int i = blockIdx.x * 256 + threadIdx.x;   // over S*2048 = 4M
    int s = i >> 11, c = i & 2047;
    float v = in[(size_t)s * 4096 + c];
    ushort h = f2bf(v);
    oh[i] = h;
    ol[i] = f2bf(v - bf2f(h));
}

// ---------------------------------------------------------------------------
// K conversion: strided fp32 (qkv cols 2048..3071) -> bf16 hi/lo [S][NKVH][HD]
// d-index XOR-swizzled per row (d ^= (s&7)<<3) for conflict-free LDS reads.
// ---------------------------------------------------------------------------
__global__ __launch_bounds__(256) void conv_k_swz_k(const float* __restrict__ in,
                                                    ushort* __restrict__ oh,
                                                    ushort* __restrict__ ol) {
    int i = blockIdx.x * 256 + threadIdx.x;      // over S*1024 = 2M
    int s = i >> 10, c = i & 1023;
    int d = c & 127;
    float v = in[(size_t)s * 4096 + 2048 + c];
    unsigned u = __float_as_uint(v);
    float hi = __uint_as_float(u & 0xFFFF0000u);
    int o = (i & ~127) + (d ^ ((s & 7) << 3));
    oh[o] = (ushort)(u >> 16);
    ol[o] = (ushort)(__float_as_uint(v - hi) >> 16);
}

// ---------------------------------------------------------------------------
// V conversion + transpose: strided fp32 (qkv cols 3072..4095) -> bf16 hi/lo
// [NKVH][HD][S], s-index XOR-swizzled within 64-blocks (s ^= (d&7)<<3).
// grid (S/64, HD/64, NKVH).
// ---------------------------------------------------------------------------
__global__ __launch_bounds__(256) void conv_vt_k(const float* __restrict__ vsrc,
                                                 ushort* __restrict__ oh,
                                                 ushort* __restrict__ ol) {
    __shared__ float t[64][65];
    int s0 = blockIdx.x * 64, d0 = blockIdx.y * 64, kvh = blockIdx.z;
    int tid = threadIdx.x;
#pragma unroll
    for (int p = 0; p < 4; ++p) {
        int c = tid + p * 256;
        int ss = c >> 4, d4 = (c & 15) * 4;
        float4 x = *(const float4*)&vsrc[(size_t)(s0 + ss) * 4096 + 3072 + kvh * 128 + d0 + d4];
        t[d4 + 0][ss] = x.x;
        t[d4 + 1][ss] = x.y;
        t[d4 + 2][ss] = x.z;
        t[d4 + 3][ss] = x.w;
    }
    __syncthreads();
#pragma unroll
    for (int p = 0; p < 4; ++p) {
        int c = tid + p * 256;
        int dd = c >> 4, s4 = (c & 15) * 4;
        int d = d0 + dd;
        int sx = s4 ^ ((d & 7) << 3);
        size_t obase = ((size_t)kvh * HD + d) * S_LEN + s0 + sx;
        ushort4 hv, lv;
        float a0 = t[dd][s4 + 0], a1 = t[dd][s4 + 1], a2 = t[dd][s4 + 2], a3 = t[dd][s4 + 3];
        unsigned u0 = __float_as_uint(a0), u1 = __float_as_uint(a1);
        unsigned u2 = __float_as_uint(a2), u3 = __float_as_uint(a3);
        hv.x = (ushort)(u0 >> 16); lv.x = (ushort)(__float_as_uint(a0 - __uint_as_float(u0 & 0xFFFF0000u)) >> 16);
        hv.y = (ushort)(u1 >> 16); lv.y = (ushort)(__float_as_uint(a1 - __uint_as_float(u1 & 0xFFFF0000u)) >> 16);
        hv.z = (ushort)(u2 >> 16); lv.z = (ushort)(__float_as_uint(a2 - __uint_as_float(u2 & 0xFFFF0000u)) >> 16);
        hv.w = (ushort)(u3 >> 16); lv.w = (ushort)(__float_as_uint(a3 - __uint_as_float(u3 & 0xFFFF0000u)) >> 16);
        *(ushort4*)&oh[obase] = hv;
        *(ushort4*)&ol[obase] = lv;
    }
}

// ---------------------------------------------------------------------------
// Transpose + split: W[K][Ntot] (cols n0..n0+Nc) -> Th/Tl rows nout0..nout0+Nc
// (each [.][K] bf16). grid (Nc/64, K/64).
// ---------------------------------------------------------------------------
__global__ __launch_bounds__(256) void transpose_split_k(const float* __restrict__ W,
                                                         ushort* __restrict__ Th,
                                                         ushort* __restrict__ Tl,
                                                         int K, int Ntot, int n0,
                                                         int nout0) {
    __shared__ float t[64][65];
    int tid = threadIdx.x;
    int nt = blockIdx.x * 64;
    int kt = blockIdx.y * 64;
#pragma unroll
    for (int p = 0; p < 4; ++p) {
        int idx = tid + p * 256;
        int kk = idx >> 4;
        int nn = (idx & 15) * 4;
        float4 v = *(const float4*)&W[(size_t)(kt + kk) * Ntot + n0 + nt + nn];
        t[nn + 0][kk] = v.x;
        t[nn + 1][kk] = v.y;
        t[nn + 2][kk] = v.z;
        t[nn + 3][kk] = v.w;
    }
    __syncthreads();
#pragma unroll
    for (int p = 0; p < 4; ++p) {
        int idx = tid + p * 256;
        int nn = idx >> 4;
        int kk = (idx & 15) * 4;
        ushort4 hv, lv;
        float a0 = t[nn][kk + 0], a1 = t[nn][kk + 1], a2 = t[nn][kk + 2], a3 = t[nn][kk + 3];
        hv.x = f2bf(a0); lv.x = f2bf(a0 - bf2f(hv.x));
        hv.y = f2bf(a1); lv.y = f2bf(a1 - bf2f(hv.y));
        hv.z = f2bf(a2); lv.z = f2bf(a2 - bf2f(hv.z));
        hv.w = f2bf(a3); lv.w = f2bf(a3 - bf2f(hv.w));
        size_t o = (size_t)(nout0 + nt + nn) * K + kt + kk;
        *(ushort4*)&Th[o] = hv;
        *(ushort4*)&Tl[o] = lv;
    }
}

// ---------------------------------------------------------------------------
// bf16x3 compensated MFMA GEMM, BM=BN=128, BK=32, 4 waves (each 64x64).
// Double-buffered LDS (64 KB), 2-phase pipeline (T3 minimal recipe):
//   STAGE(next) -> ds_read/MFMA(cur) -> one barrier -> swap.
// Next-tile HBM loads overlap the MFMA phase; one barrier per K-step.
// ---------------------------------------------------------------------------
__global__ __launch_bounds__(256, 2) void gemm_bf16x3(
    const ushort* __restrict__ Ah, const ushort* __restrict__ Al,
    const ushort* __restrict__ Bh, const ushort* __restrict__ Bl,
    const float* __restrict__ res, float* __restrict__ C,
    int M, int N, int K) {
    __shared__ __align__(16) ushort sAh[2][128 * 32];
    __shared__ __align__(16) ushort sAl[2][128 * 32];
    __shared__ __align__(16) ushort sBh[2][128 * 32];
    __shared__ __align__(16) ushort sBl[2][128 * 32];

    // bijective XCD swizzle (grid size is a multiple of 8)
    unsigned nbx = gridDim.x;
    unsigned flat = blockIdx.y * nbx + blockIdx.x;
    unsigned cpx = (nbx * gridDim.y) >> 3;
    unsigned sflat = (flat & 7u) * cpx + (flat >> 3);
    int bx = (int)(sflat % nbx);
    int by = (int)(sflat / nbx);
    int bm = by * 128, bn = bx * 128;

    int tid = threadIdx.x;
    int lane = tid & 63, wave = tid >> 6;
    int wr = wave >> 1, wc = wave & 1;
    int r = lane & 15, kq = lane >> 4;

    // staging: each tile (128x32 bf16 = 8KB) = 512 16B-chunks = 2/thread
    int srow = tid >> 2;
    int sk = (tid & 3) * 8;
    const ushort* gAh = Ah + (size_t)(bm + srow) * K + sk;
    const ushort* gAl = Al + (size_t)(bm + srow) * K + sk;
    const ushort* gBh = Bh + (size_t)(bn + srow) * K + sk;
    const ushort* gBl = Bl + (size_t)(bn + srow) * K + sk;
    const size_t rstep = (size_t)64 * K;

    f32x4 acc[4][4] = {};

    auto STAGE = [&](int buf, int k0) {
        glds16(gAh + k0, &sAh[buf][tid * 8]);
        glds16(gAh + k0 + rstep, &sAh[buf][2048 + tid * 8]);
        glds16(gAl + k0, &sAl[buf][tid * 8]);
        glds16(gAl + k0 + rstep, &sAl[buf][2048 + tid * 8]);
        glds16(gBh + k0, &sBh[buf][tid * 8]);
        glds16(gBh + k0 + rstep, &sBh[buf][2048 + tid * 8]);
        glds16(gBl + k0, &sBl[buf][tid * 8]);
        glds16(gBl + k0 + rstep, &sBl[buf][2048 + tid * 8]);
    };
    auto COMPUTE = [&](int buf) {
        const ushort* pAh = &sAh[buf][(wr * 64 + r) * 32 + kq * 8];
        const ushort* pAl = &sAl[buf][(wr * 64 + r) * 32 + kq * 8];
        const ushort* pBh = &sBh[buf][(wc * 64 + r) * 32 + kq * 8];
        const ushort* pBl = &sBl[buf][(wc * 64 + r) * 32 + kq * 8];
        bf16x8 ah[4], al[4];
#pragma unroll
        for (int mi = 0; mi < 4; ++mi) {
            ah[mi] = *(const bf16x8*)(pAh + mi * 512);
            al[mi] = *(const bf16x8*)(pAl + mi * 512);
        }
#pragma unroll
        for (int ni = 0; ni < 4; ++ni) {
            bf16x8 bh = *(const bf16x8*)(pBh + ni * 512);
            bf16x8 bl = *(const bf16x8*)(pBl + ni * 512);
#pragma unroll
            for (int mi = 0; mi < 4; ++mi) {
                acc[mi][ni] = __builtin_amdgcn_mfma_f32_16x16x32_bf16(ah[mi], bh, acc[mi][ni], 0, 0, 0);
                acc[mi][ni] = __builtin_amdgcn_mfma_f32_16x16x32_bf16(al[mi], bh, acc[mi][ni], 0, 0, 0);
                acc[mi][ni] = __builtin_amdgcn_mfma_f32_16x16x32_bf16(ah[mi], bl, acc[mi][ni], 0, 0, 0);
            }
        }
    };

    STAGE(0, 0);
    __syncthreads();   // prologue drain: buf0 resident
    int cur = 0;
    for (int k0 = 32; k0 < K; k0 += 32) {
        STAGE(cur ^ 1, k0);   // next tile in flight during compute
        COMPUTE(cur);
        __syncthreads();      // drains vmcnt (next tile ready) + LDS reads done
        cur ^= 1;
    }
    COMPUTE(cur);

    // epilogue; C/D layout: col = lane&15, row = (lane>>4)*4 + j
    int c0 = bn + wc * 64 + r;
    int r0 = bm + wr * 64 + kq * 4;
#pragma unroll
    for (int mi = 0; mi < 4; ++mi)
#pragma unroll
        for (int ni = 0; ni < 4; ++ni)
#pragma unroll
            for (int j = 0; j < 4; ++j) {
                int row = r0 + mi * 16 + j;
                int col = c0 + ni * 16;
                size_t idx = (size_t)row * N + col;
                float val = acc[mi][ni][j];
                if (res) val += res[idx];
                C[idx] = val;
            }
}

// ---------------------------------------------------------------------------
// Per-head RMSNorm (over HD=128) + RoPE, in place, strided rows.
// ---------------------------------------------------------------------------
__global__ __launch_bounds__(128) void qk_norm_rope_k(float* __restrict__ qk,
                                                      const float* __restrict__ nw,
                                                      const int* __restrict__ positions,
                                                      int stride) {
    int s = blockIdx.x;
    int h = blockIdx.y;
    int d = threadIdx.x;
    float* row = qk + (size_t)s * stride + (size_t)h * HD;
    __shared__ float buf[HD];
    __shared__ float red[HD];
    float v = row[d];
    red[d] = v * v;
    __syncthreads();
    for (int off = 64; off > 0; off >>= 1) {
        if (d < off) red[d] += red[d + off];
        __syncthreads();
    }
    float r = rsqrtf(red[0] / (float)HD + EPSV);
    float nv = v * r * nw[d];
    buf[d] = nv;
    __syncthreads();
    float pos = (float)positions[s];
    int d2 = d & 63;
    float inv_freq = expf(-((float)(2 * d2) / 128.0f) * 13.815510557964274f);
    float freq = pos * inv_freq;
    float c, sn;
    sincosf(freq, &sn, &c);
    float rot = (d < 64) ? -buf[d + 64] : buf[d - 64];
    row[d] = nv * c + rot * sn;
}

// ---------------------------------------------------------------------------
// MFMA flash attention, bf16x3 compensated (verified rounds 1-3).
// ---------------------------------------------------------------------------
#define ATQ 64
#define ATK 64

__global__ __launch_bounds__(256, 2) void attn_mfma_k(
    const ushort* __restrict__ Qhg, const ushort* __restrict__ Qlg,
    const ushort* __restrict__ Khg, const ushort* __restrict__ Klg,
    const ushort* __restrict__ Vhg, const ushort* __restrict__ Vlg,
    const int* __restrict__ keys_idxs, const int* __restrict__ hs_idxs,
    ushort* __restrict__ Chg, ushort* __restrict__ Clg) {
    __shared__ __align__(16) ushort sKh[64 * 128];   // also P overlay (4 x 2048)
    __shared__ __align__(16) ushort sKl[64 * 128];
    __shared__ __align__(16) ushort sVh[128 * 64];
    __shared__ __align__(16) ushort sVl[128 * 64];
    __shared__ int kidx[ATK];
    __shared__ int qpos[ATQ];

    int bx = blockIdx.x;
    int qt = (bx & 1) ? (31 - (bx >> 1)) : (bx >> 1);
    int h = blockIdx.y;
    int kvh = h >> 1;
    int tid = threadIdx.x;
    int lane = tid & 63, wv = tid >> 6;
    int q0 = qt * ATQ;
    int r = lane & 15, kq = lane >> 4;
    int xorv = (lane & 7) << 3;
    const float scale = 0.088388347648318447f;

    bf16x8 qh[4], ql[4];
    {
        const ushort* qb = Qhg + ((size_t)(q0 + wv * 16 + r) * NHEADS + h) * HD + kq * 8;
        const ushort* qb2 = Qlg + ((size_t)(q0 + wv * 16 + r) * NHEADS + h) * HD + kq * 8;
#pragma unroll
        for (int ks = 0; ks < 4; ++ks) {
            qh[ks] = *(const bf16x8*)(qb + ks * 32);
            ql[ks] = *(const bf16x8*)(qb2 + ks * 32);
        }
    }
    if (tid < ATQ) qpos[tid] = hs_idxs[q0 + tid];

    const size_t kvstride = (size_t)NKVH * HD;   // 1024
    const ushort* gKh = Khg + ((size_t)(tid >> 4) * NKVH + kvh) * HD + (tid & 15) * 8;
    const ushort* gKl = Klg + ((size_t)(tid >> 4) * NKVH + kvh) * HD + (tid & 15) * 8;
    const ushort* gVh = Vhg + ((size_t)kvh * HD + (tid >> 3)) * S_LEN + (tid & 7) * 8;
    const ushort* gVl = Vlg + ((size_t)kvh * HD + (tid >> 3)) * S_LEN + (tid & 7) * 8;

    f32x4 o[8] = {};
    float m_run[4] = {-3.0e38f, -3.0e38f, -3.0e38f, -3.0e38f};
    float l_run[4] = {0.0f, 0.0f, 0.0f, 0.0f};

    __syncthreads();
    int hs_max = qpos[ATQ - 1];
    int qp[4];
#pragma unroll
    for (int j = 0; j < 4; ++j) qp[j] = qpos[wv * 16 + kq * 4 + j];

    for (int kt = 0; kt < S_LEN / ATK; ++kt) {
        int k0 = kt * ATK;
        if (keys_idxs[k0] > hs_max) break;
        __syncthreads();
        const size_t koff = (size_t)k0 * kvstride;
#pragma unroll
        for (int p = 0; p < 4; ++p) {
            glds16(gKh + koff + (size_t)p * 16 * kvstride, sKh + (tid + p * 256) * 8);
            glds16(gKl + koff + (size_t)p * 16 * kvstride, sKl + (tid + p * 256) * 8);
            glds16(gVh + k0 + (size_t)p * 32 * S_LEN, sVh + (tid + p * 256) * 8);
            glds16(gVl + k0 + (size_t)p * 32 * S_LEN, sVl + (tid + p * 256) * 8);
        }
        if (tid < ATK) kidx[tid] = keys_idxs[k0 + tid];
        __syncthreads();

        f32x4 sf[4] = {};
#pragma unroll
        for (int ks = 0; ks < 4; ++ks) {
            int kb = (ks * 32 + kq * 8) ^ xorv;
#pragma unroll
            for (int f = 0; f < 4; ++f) {
                bf16x8 kh = *(const bf16x8*)(sKh + (f * 16 + r) * 128 + kb);
                bf16x8 kl = *(const bf16x8*)(sKl + (f * 16 + r) * 128 + kb);
                sf[f] = __builtin_amdgcn_mfma_f32_16x16x32_bf16(qh[ks], kh, sf[f], 0, 0, 0);
                sf[f] = __builtin_amdgcn_mfma_f32_16x16x32_bf16(ql[ks], kh, sf[f], 0, 0, 0);
                sf[f] = __builtin_amdgcn_mfma_f32_16x16x32_bf16(qh[ks], kl, sf[f], 0, 0, 0);
            }
        }

        int kj[4];
#pragma unroll
        for (int f = 0; f < 4; ++f) kj[f] = kidx[f * 16 + r];
        float alj[4];
#pragma unroll
        for (int j = 0; j < 4; ++j) {
#pragma unroll
            for (int f = 0; f < 4; ++f)
                sf[f][j] = sf[f][j] * scale + ((kj[f] <= qp[j]) ? 0.0f : -1.0e9f);
            float m0 = fmaxf(fmaxf(sf[0][j], sf[1][j]), fmaxf(sf[2][j], sf[3][j]));
#pragma unroll
            for (int off = 1; off < 16; off <<= 1) m0 = fmaxf(m0, __shfl_xor(m0, off));
            float mn = fmaxf(m_run[j], m0);
            alj[j] = __expf(m_run[j] - mn);
            m_run[j] = mn;
            float rsum = 0.0f;
#pragma unroll
            for (int f = 0; f < 4; ++f) {
                sf[f][j] = __expf(sf[f][j] - mn);
                rsum += sf[f][j];
            }
#pragma unroll
            for (int off = 1; off < 16; off <<= 1) rsum += __shfl_xor(rsum, off);
            l_run[j] = l_run[j] * alj[j] + rsum;
        }
#pragma unroll
        for (int df = 0; df < 8; ++df)
#pragma unroll
            for (int j = 0; j < 4; ++j) o[df][j] *= alj[j];

        __syncthreads();

        ushort* sPh = sKh + wv * 2048;
        ushort* sPl = sPh + 1024;
#pragma unroll
        for (int j = 0; j < 4; ++j) {
            int qloc = kq * 4 + j;
            int swz = (qloc & 7) << 3;
            int rowb = qloc * 64;
#pragma unroll
            for (int f = 0; f < 4; ++f) {
                float pv = sf[f][j];
                unsigned u = __float_as_uint(pv);
                float hi = __uint_as_float(u & 0xFFFF0000u);
                int a = rowb + ((f * 16 + r) ^ swz);
                sPh[a] = (ushort)(u >> 16);
                sPl[a] = (ushort)(__float_as_uint(pv - hi) >> 16);
            }
        }

#pragma unroll
        for (int kv0 = 0; kv0 < 2; ++kv0) {
            int kb = (kv0 * 32 + kq * 8) ^ xorv;
            bf16x8 pah = *(const bf16x8*)(sPh + r * 64 + kb);
            bf16x8 pal = *(const bf16x8*)(sPl + r * 64 + kb);
#pragma unroll
            for (int df = 0; df < 8; ++df) {
                bf16x8 vh = *(const bf16x8*)(sVh + (df * 16 + r) * 64 + kb);
                bf16x8 vl = *(const bf16x8*)(sVl + (df * 16 + r) * 64 + kb);
                o[df] = __builtin_amdgcn_mfma_f32_16x16x32_bf16(pah, vh, o[df], 0, 0, 0);
                o[df] = __builtin_amdgcn_mfma_f32_16x16x32_bf16(pal, vh, o[df], 0, 0, 0);
                o[df] = __builtin_amdgcn_mfma_f32_16x16x32_bf16(pah, vl, o[df], 0, 0, 0);
            }
        }
    }

    // epilogue: normalize + bf16 hi/lo split store (feeds o-proj A operand)
#pragma unroll
    for (int j = 0; j < 4; ++j) {
        float invl = 1.0f / l_run[j];
        int qg = q0 + wv * 16 + kq * 4 + j;
#pragma unroll
        for (int df = 0; df < 8; ++df) {
            int d = df * 16 + r;
            float val = o[df][j] * invl;
            size_t idx = ((size_t)qg * NHEADS + h) * HD + d;
            ushort hh = f2bf(val);
            Chg[idx] = hh;
            Clg[idx] = f2bf(val - bf2f(hh));
        }
    }
}

// ---------------------------------------------------------------------------
// Importance: softmax (no mask) of last q row vs all keys, per head (strided).
// ---------------------------------------------------------------------------
__global__ __launch_bounds__(256) void importance_scores_k(const float* __restrict__ q,
                                                           const float* __restrict__ k,
                                                           float* __restrict__ imp_ws,
                                                           int stride) {
    int h = blockIdx.x;
    int kv = h >> 1;
    int tid = threadIdx.x;
    __shared__ float qrow[HD];
    __shared__ float sc[S_LEN];
    __shared__ float red[256];
    const float* qp = q + (size_t)(S_LEN - 1) * stride + (size_t)h * HD;
    if (tid < HD) qrow[tid] = qp[tid];
    __syncthreads();
    const float scale = 0.088388347648318447f;
    float lmax = -3.0e38f;
#pragma unroll
    for (int rep = 0; rep < 8; ++rep) {
        int j = tid + rep * 256;
        const float* kp = k + (size_t)j * stride + (size_t)kv * HD;
        float dot = 0.0f;
        for (int d = 0; d < HD; ++d) dot += qrow[d] * kp[d];
        float sval = dot * scale;
        sc[j] = sval;
        lmax = fmaxf(lmax, sval);
    }
    red[tid] = lmax;
    __syncthreads();
    for (int off = 128; off > 0; off >>= 1) {
        if (tid < off) red[tid] = fmaxf(red[tid], red[tid + off]);
        __syncthreads();
    }
    float m = red[0];
    __syncthreads();
    float lsum = 0.0f;
    float evals[8];
#pragma unroll
    for (int rep = 0; rep < 8; ++rep) {
        int j = tid + rep * 256;
        float e = expf(sc[j] - m);
        evals[rep] = e;
        lsum += e;
    }
    red[tid] = lsum;
    __syncthreads();
    for (int off = 128; off > 0; off >>= 1) {
        if (tid < off) red[tid] += red[tid + off];
        __syncthreads();
    }
    float inv = 1.0f / red[0];
#pragma unroll
    for (int rep = 0; rep < 8; ++rep) {
        int j = tid + rep * 256;
        imp_ws[(size_t)h * S_LEN + j] = evals[rep] * inv;
    }
}

__global__ __launch_bounds__(256) void importance_combine_k(const float* __restrict__ imp_ws,
                                                            float* __restrict__ out) {
    int j = blockIdx.x * 256 + threadIdx.x;
    float sum = 0.0f;
    for (int h = 0; h < NHEADS; ++h) sum += imp_ws[(size_t)h * S_LEN + j];
    out[j] = (j == S_LEN - 1) ? 3.0e38f : sum * (1.0f / NHEADS);
}

// ---------------------------------------------------------------------------
// SiLU(g)*u from fused gu buffer [S][4096] -> Dh/Dl bf16 split [S][2048]
// ---------------------------------------------------------------------------
__global__ __launch_bounds__(256) void silu_split_k(const float* __restrict__ gu,
                                                    ushort* __restrict__ dh,
                                                    ushort* __restrict__ dl) {
    int i = blockIdx.x * 256 + threadIdx.x;   // over S*2048 = 4M
    int s = i >> 11, c = i & 2047;
    const float* row = gu + (size_t)s * 4096;
    float g = row[c], u = row[c + 2048];
    float d = g / (1.0f + expf(-g)) * u;
    ushort hh = f2bf(d);
    dh[i] = hh;
    dl[i] = f2bf(d - bf2f(hh));
}

// ---------------------------------------------------------------------------
extern "C" void kernel_launch(void* const* d_in, const int* in_sizes, int n_in,
                              void* d_out, int out_size, void* d_ws, size_t ws_size,
                              hipStream_t stream) {
    const float* hidden    = (const float*)d_in[0];
    const int*   keys_idxs = (const int*)d_in[2];
    const int*   hs_idxs   = (const int*)d_in[3];
    const int*   positions = (const int*)d_in[4];
    const float* ln_in_w   = (const float*)d_in[5];
    const float* q_w       = (const float*)d_in[6];
    const float* k_w       = (const float*)d_in[7];
    const float* v_w       = (const float*)d_in[8];
    const float* q_norm_w  = (const float*)d_in[9];
    const float* k_norm_w  = (const float*)d_in[10];
    const float* o_w       = (const float*)d_in[11];
    const float* ln_post_w = (const float*)d_in[12];
    const float* gate_w    = (const float*)d_in[13];
    const float* up_w      = (const float*)d_in[14];
    const float* down_w    = (const float*)d_in[15];

    float* out = (float*)d_out;
    float* ws = (float*)d_ws;
    const size_t MF = 1024ull * 1024;

    // Region plan (floats; peak 20 MF = 80 MB):
    //  [0,4M)    Xh/Xl bf16  -> Qbh/Qbl bf16 -> Yh/Yl bf16
    //  [4M,12M)  Wqkv h/l    -> Kb/Vt ([4M,8M)) + imp ([8M,..))
    //                        -> Wo ([4M,8M)) -> Wgu ([4M,12M))
    //                        -> D ([4M,8M)) + Wdown ([8M,12M))
    //  [12M,20M) qkv fp32 [2048][4096]
    //                        -> Ch/Cl ([12M,16M)) + hb ([16M,20M))
    //                        -> gu fp32 [2048][4096]
    ushort* Xh  = (ushort*)(ws);
    ushort* Xl  = (ushort*)(ws + 2 * MF);
    ushort* Wh  = (ushort*)(ws + 4 * MF);       // qkv/gu: 8M elems per half
    ushort* Wl  = (ushort*)(ws + 8 * MF);
    float*  qkv = ws + 12 * MF;                 // [2048][4096]
    ushort* Qbh = (ushort*)(ws);
    ushort* Qbl = (ushort*)(ws + 2 * MF);
    ushort* Kbh = (ushort*)(ws + 4 * MF);
    ushort* Kbl = (ushort*)(ws + 5 * MF);
    ushort* Vth = (ushort*)(ws + 6 * MF);
    ushort* Vtl = (ushort*)(ws + 7 * MF);
    float*  imp = ws + 8 * MF;
    ushort* Woh = (ushort*)(ws + 4 * MF);       // 4M elems per half
    ushort* Wol = (ushort*)(ws + 6 * MF);
    ushort* Ch  = (ushort*)(ws + 12 * MF);
    ushort* Cl  = (ushort*)(ws + 14 * MF);
    float*  hb  = ws + 16 * MF;
    ushort* Yh  = (ushort*)(ws);
    ushort* Yl  = (ushort*)(ws + 2 * MF);
    float*  gu  = ws + 12 * MF;                 // [2048][4096]
    ushort* Dh  = (ushort*)(ws + 4 * MF);
    ushort* Dl  = (ushort*)(ws + 6 * MF);
    ushort* Wdh = (ushort*)(ws + 8 * MF);
    ushort* Wdl = (ushort*)(ws + 10 * MF);

    // 1. x = rms(hidden) -> bf16 split
    rmsnorm_split_k<<<S_LEN, 256, 0, stream>>>(hidden, ln_in_w, Xh, Xl);

    // 2. fused QKV projection: B rows 0..2047 = q_w, 2048..3071 = k_w, 3072.. = v_w
    transpose_split_k<<<dim3(32, 32), 256, 0, stream>>>(q_w, Wh, Wl, HDIM, HDIM, 0, 0);
    transpose_split_k<<<dim3(16, 32), 256, 0, stream>>>(k_w, Wh, Wl, HDIM, 1024, 0, 2048);
    transpose_split_k<<<dim3(16, 32), 256, 0, stream>>>(v_w, Wh, Wl, HDIM, 1024, 0, 3072);
    gemm_bf16x3<<<dim3(4096 / 128, S_LEN / 128), 256, 0, stream>>>(
        Xh, Xl, Wh, Wl, nullptr, qkv, S_LEN, 4096, HDIM);

    // 3. per-head norm + rope on q (cols 0..2047) and k (cols 2048..3071)
    qk_norm_rope_k<<<dim3(S_LEN, NHEADS), 128, 0, stream>>>(qkv, q_norm_w, positions, 4096);
    qk_norm_rope_k<<<dim3(S_LEN, NKVH), 128, 0, stream>>>(qkv + 2048, k_norm_w, positions, 4096);

    // 4. importance (fp32 q,k in qkv; before conversions reuse regions)
    importance_scores_k<<<NHEADS, 256, 0, stream>>>(qkv, qkv + 2048, imp, 4096);
    importance_combine_k<<<S_LEN / 256, 256, 0, stream>>>(imp, out + (size_t)S_LEN * HDIM);

    // 5. convert q/k/v to bf16 hi/lo attention layouts
    conv_q_k<<<(S_LEN * 2048) / 256, 256, 0, stream>>>(qkv, Qbh, Qbl);
    conv_k_swz_k<<<(S_LEN * 1024) / 256, 256, 0, stream>>>(qkv, Kbh, Kbl);
    conv_vt_k<<<dim3(S_LEN / 64, HD / 64, NKVH), 256, 0, stream>>>(qkv, Vth, Vtl);

    // 6. MFMA flash attention -> Ch/Cl (bf16 split; qkv fp32 now dead)
    attn_mfma_k<<<dim3(S_LEN / ATQ, NHEADS), 256, 0, stream>>>(
        Qbh, Qbl, Kbh, Kbl, Vth, Vtl, keys_idxs, hs_idxs, Ch, Cl);

    // 7. h = hidden + ctx @ o_w
    transpose_split_k<<<dim3(32, 32), 256, 0, stream>>>(o_w, Woh, Wol, HDIM, HDIM, 0, 0);
    gemm_bf16x3<<<dim3(HDIM / 128, S_LEN / 128), 256, 0, stream>>>(
        Ch, Cl, Woh, Wol, hidden, hb, S_LEN, HDIM, HDIM);

    // 8. out = h (residual base for chunked down-proj accumulation)
    hipMemcpyAsync(out, hb, (size_t)S_LEN * HDIM * sizeof(float),
                   hipMemcpyDeviceToDevice, stream);

    // 9. y = rms(h) -> bf16 split
    rmsnorm_split_k<<<S_LEN, 256, 0, stream>>>(hb, ln_post_w, Yh, Yl);

    // 10. MLP in three FF-chunks of 2048; gate+up fused into one N=4096 GEMM
    for (int c = 0; c < 3; ++c) {
        transpose_split_k<<<dim3(32, 32), 256, 0, stream>>>(gate_w, Wh, Wl, HDIM, FFDIM, c * 2048, 0);
        transpose_split_k<<<dim3(32, 32), 256, 0, stream>>>(up_w, Wh, Wl, HDIM, FFDIM, c * 2048, 2048);
        gemm_bf16x3<<<dim3(4096 / 128, S_LEN / 128), 256, 0, stream>>>(
            Yh, Yl, Wh, Wl, nullptr, gu, S_LEN, 4096, HDIM);
        silu_split_k<<<(S_LEN * 2048) / 256, 256, 0, stream>>>(gu, Dh, Dl);
        transpose_split_k<<<dim3(32, 32), 256, 0, stream>>>(
            down_w + (size_t)c * 2048 * HDIM, Wdh, Wdl, 2048, HDIM, 0, 0);
        gemm_bf16x3<<<dim3(HDIM / 128, S_LEN / 128), 256, 0, stream>>>(
            Dh, Dl, Wdh, Wdl, out, out, S_LEN, HDIM, 2048);
    }
}